// Round 7
// baseline (266.189 us; speedup 1.0000x reference)
//
#include <hip/hip_runtime.h>

// GNN encoder: input MLP + LN, 2x SAGEConv(mean) + ReLU + residual + LN, classifier MLP.
// Round 7: attack latency/occupancy (round-6 counters: sage_cls 52us @ 13% occ, 3.6% MFMA).
//  - dense kernels: 64 rows/block (grid 782 vs 391), 1 row-tile/wave, LDS [64][136]
//  - gather: quarter-wave per node (4 nodes/wave), 4 edge-rows in flight, no shuffles
//  - keeps round-6 fusions: k_mlp (MLP+LN), k_sage0, k_sage_cls (SAGE+classifier)

namespace {

constexpr int NN = 50000;
constexpr int EE = 640000;
constexpr int HH = 128;
constexpr int CC = 40;
constexpr int SCAN_NB = (NN + 255) / 256;  // 196

typedef unsigned short u16;
typedef __attribute__((ext_vector_type(8))) short s16x8;
typedef __attribute__((ext_vector_type(8))) unsigned short u16x8;
typedef __attribute__((ext_vector_type(4))) float f32x4;

__device__ __forceinline__ float b2f(u16 h) {
  unsigned int u = ((unsigned int)h) << 16;
  return __builtin_bit_cast(float, u);
}
__device__ __forceinline__ u16 f2b(float f) {
  unsigned int u = __builtin_bit_cast(unsigned int, f);
  u += 0x7FFFu + ((u >> 16) & 1u);
  return (u16)(u >> 16);
}

// ---------------- CSR build ----------------
__global__ void k_degree(const int* __restrict__ ei, int* __restrict__ cnt) {
  int e = blockIdx.x * 256 + threadIdx.x;
  if (e < EE) atomicAdd(&cnt[ei[EE + e]], 1);
}

__global__ void k_scan_block(const int* __restrict__ cnt, int* __restrict__ rowptr,
                             int* __restrict__ bsum, float* __restrict__ inv) {
  __shared__ int s[256];
  const int t = threadIdx.x;
  const int i = blockIdx.x * 256 + t;
  const int v = i < NN ? cnt[i] : 0;
  s[t] = v;
  __syncthreads();
  for (int off = 1; off < 256; off <<= 1) {
    int add = t >= off ? s[t - off] : 0;
    __syncthreads();
    s[t] += add;
    __syncthreads();
  }
  if (i < NN) {
    rowptr[i] = s[t] - v;
    inv[i] = v > 0 ? 1.0f / (float)v : 0.0f;
  }
  if (t == 255) bsum[blockIdx.x] = s[255];
}

__global__ void k_scan_tops(int* __restrict__ bsum) {
  __shared__ int s[256];
  const int t = threadIdx.x;
  const int v = t < SCAN_NB ? bsum[t] : 0;
  s[t] = v;
  __syncthreads();
  for (int off = 1; off < 256; off <<= 1) {
    int add = t >= off ? s[t - off] : 0;
    __syncthreads();
    s[t] += add;
    __syncthreads();
  }
  if (t < SCAN_NB) bsum[t] = s[t] - v;
}

__global__ void k_scan_add(int* __restrict__ rowptr, const int* __restrict__ bsum) {
  const int i = blockIdx.x * 256 + threadIdx.x;
  if (i < NN) rowptr[i] += bsum[blockIdx.x];
  if (i == 0) rowptr[NN] = EE;
}

__global__ void k_fill(const int* __restrict__ ei, const int* __restrict__ rowptr,
                       int* __restrict__ cursor, int* __restrict__ col) {
  int e = blockIdx.x * 256 + threadIdx.x;
  if (e >= EE) return;
  int s = ei[e];
  int d = ei[EE + e];
  int pos = atomicAdd(&cursor[d], 1);
  col[rowptr[d] + pos] = s;
}

// transpose+cast all weights into wt slots {pw1,pw2,wl0,wl1,wr0,wr1,cw1,cw2T}
__global__ void k_prep_w(const float* __restrict__ pw1, const float* __restrict__ pw2,
                         const float* __restrict__ swl, const float* __restrict__ swr,
                         const float* __restrict__ cw1, const float* __restrict__ cw2,
                         u16* __restrict__ wt) {
  int flat = blockIdx.x * 256 + threadIdx.x;
  const int SEVEN = 7 * 16384;
  if (flat < SEVEN) {
    int id = flat >> 14;
    int off = flat & 16383;
    int n = off >> 7, k = off & 127;
    const float* s;
    switch (id) {
      case 0: s = pw1; break;
      case 1: s = pw2; break;
      case 2: s = swl; break;
      case 3: s = swl + 16384; break;
      case 4: s = swr; break;
      case 5: s = swr + 16384; break;
      default: s = cw1; break;
    }
    wt[(size_t)id * 16384 + n * 128 + k] = f2b(s[k * 128 + n]);
  } else {
    int off = flat - SEVEN;
    if (off < CC * 128) {
      int n = off >> 7, k = off & 127;
      wt[(size_t)7 * 16384 + n * 128 + k] = f2b(cw2[k * CC + n]);
    }
  }
}

// ---------------- aggregation: quarter-wave per node, 4 edges in flight ----------------
__global__ __launch_bounds__(256) void k_gather_q(
    const u16* __restrict__ hb, const int* __restrict__ rowptr,
    const int* __restrict__ col, const float* __restrict__ inv,
    u16* __restrict__ agg) {
  const int tid = threadIdx.x;
  const int node = blockIdx.x * 16 + (tid >> 4);
  if (node >= NN) return;
  const int ln = tid & 15;
  const int cl = ln * 8;
  const int start = rowptr[node];
  const int end = rowptr[node + 1];
  float a[8] = {0.f, 0.f, 0.f, 0.f, 0.f, 0.f, 0.f, 0.f};
  int i = start;
  for (; i + 4 <= end; i += 4) {
    const int s0 = col[i], s1 = col[i + 1], s2 = col[i + 2], s3 = col[i + 3];
    const u16x8 v0 = *reinterpret_cast<const u16x8*>(&hb[(size_t)s0 * HH + cl]);
    const u16x8 v1 = *reinterpret_cast<const u16x8*>(&hb[(size_t)s1 * HH + cl]);
    const u16x8 v2 = *reinterpret_cast<const u16x8*>(&hb[(size_t)s2 * HH + cl]);
    const u16x8 v3 = *reinterpret_cast<const u16x8*>(&hb[(size_t)s3 * HH + cl]);
#pragma unroll
    for (int k = 0; k < 8; ++k)
      a[k] += (b2f(v0[k]) + b2f(v1[k])) + (b2f(v2[k]) + b2f(v3[k]));
  }
  for (; i < end; ++i) {
    const int s0 = col[i];
    const u16x8 v0 = *reinterpret_cast<const u16x8*>(&hb[(size_t)s0 * HH + cl]);
#pragma unroll
    for (int k = 0; k < 8; ++k) a[k] += b2f(v0[k]);
  }
  const float sc = inv[node];
  u16x8 o;
#pragma unroll
  for (int k = 0; k < 8; ++k) o[k] = f2b(a[k] * sc);
  *reinterpret_cast<u16x8*>(&agg[(size_t)node * HH + cl]) = o;
}

// ---------------- fused input MLP: h = LN(relu(x@pw1+pb1)@pw2+pb2) ----------------
__global__ __launch_bounds__(256) void k_mlp(
    const float* __restrict__ x, const u16* __restrict__ WT1,
    const float* __restrict__ pb1, const u16* __restrict__ WT2,
    const float* __restrict__ pb2, const float* __restrict__ lg,
    const float* __restrict__ lb, u16* __restrict__ hb) {
  __shared__ u16 t1[64][136];
  const int tid = threadIdx.x;
  const int wv = tid >> 6, ln = tid & 63;
  const int lrow = ln & 15, kg = ln >> 4;
  const int tbase = blockIdx.x * 64 + wv * 16;
  const int lb0 = wv * 16;
  const int ar = min(tbase + lrow, NN - 1);

  f32x4 acc[8];
#pragma unroll
  for (int cf = 0; cf < 8; ++cf) acc[cf] = (f32x4){0.f, 0.f, 0.f, 0.f};

#pragma unroll
  for (int ks = 0; ks < 4; ++ks) {
    const float4* p0 = reinterpret_cast<const float4*>(x + (size_t)ar * 128 + ks * 32 + kg * 8);
    float4 x0 = p0[0], x1 = p0[1];
    s16x8 a0;
    a0[0] = (short)f2b(x0.x); a0[1] = (short)f2b(x0.y); a0[2] = (short)f2b(x0.z); a0[3] = (short)f2b(x0.w);
    a0[4] = (short)f2b(x1.x); a0[5] = (short)f2b(x1.y); a0[6] = (short)f2b(x1.z); a0[7] = (short)f2b(x1.w);
#pragma unroll
    for (int cf = 0; cf < 8; ++cf) {
      const s16x8 bf = *reinterpret_cast<const s16x8*>(WT1 + (size_t)(cf * 16 + lrow) * 128 + ks * 32 + kg * 8);
      acc[cf] = __builtin_amdgcn_mfma_f32_16x16x32_bf16(a0, bf, acc[cf], 0, 0, 0);
    }
  }

  {
    float bb[8];
#pragma unroll
    for (int cf = 0; cf < 8; ++cf) bb[cf] = pb1[cf * 16 + lrow];
#pragma unroll
    for (int j = 0; j < 4; ++j) {
      const int lr = lb0 + kg * 4 + j;
#pragma unroll
      for (int cf = 0; cf < 8; ++cf)
        t1[lr][cf * 16 + lrow] = f2b(fmaxf(acc[cf][j] + bb[cf], 0.0f));
    }
  }
  __syncthreads();

  // phase 2: h = LN(t1 @ pw2 + pb2)
  f32x4 c0[8];
#pragma unroll
  for (int cf = 0; cf < 8; ++cf) c0[cf] = (f32x4){0.f, 0.f, 0.f, 0.f};
#pragma unroll
  for (int ks = 0; ks < 4; ++ks) {
    const s16x8 a0 = *reinterpret_cast<const s16x8*>(&t1[lb0 + lrow][ks * 32 + kg * 8]);
#pragma unroll
    for (int cf = 0; cf < 8; ++cf) {
      const s16x8 bf = *reinterpret_cast<const s16x8*>(WT2 + (size_t)(cf * 16 + lrow) * 128 + ks * 32 + kg * 8);
      c0[cf] = __builtin_amdgcn_mfma_f32_16x16x32_bf16(a0, bf, c0[cf], 0, 0, 0);
    }
  }

  float bb[8], gm[8], gb[8];
#pragma unroll
  for (int cf = 0; cf < 8; ++cf) {
    const int c = cf * 16 + lrow;
    bb[cf] = pb2[c];
    gm[cf] = lg[c];
    gb[cf] = lb[c];
  }
#pragma unroll
  for (int j = 0; j < 4; ++j) {
    const int r = tbase + kg * 4 + j;
    float v[8];
#pragma unroll
    for (int cf = 0; cf < 8; ++cf) v[cf] = c0[cf][j] + bb[cf];
    float s = 0.f;
#pragma unroll
    for (int cf = 0; cf < 8; ++cf) s += v[cf];
    s += __shfl_xor(s, 1); s += __shfl_xor(s, 2);
    s += __shfl_xor(s, 4); s += __shfl_xor(s, 8);
    const float mu = s * (1.0f / 128);
    float q = 0.f;
#pragma unroll
    for (int cf = 0; cf < 8; ++cf) { const float d = v[cf] - mu; q += d * d; }
    q += __shfl_xor(q, 1); q += __shfl_xor(q, 2);
    q += __shfl_xor(q, 4); q += __shfl_xor(q, 8);
    const float istd = rsqrtf(q * (1.0f / 128) + 1e-5f);
    if (r < NN) {
#pragma unroll
      for (int cf = 0; cf < 8; ++cf)
        hb[(size_t)r * 128 + cf * 16 + lrow] = f2b((v[cf] - mu) * istd * gm[cf] + gb[cf]);
    }
  }
}

// ---------------- SAGE layer 0: h' = LN(h + relu(agg@WL + bl + h@WR)) -> hb ----------------
__global__ __launch_bounds__(256) void k_sage0(
    const u16* __restrict__ agg, const u16* __restrict__ hb,
    const u16* __restrict__ WTl, const u16* __restrict__ WTr,
    const float* __restrict__ bl, const float* __restrict__ lg,
    const float* __restrict__ lb, u16* __restrict__ hb_out) {
  const int tid = threadIdx.x;
  const int wv = tid >> 6, ln = tid & 63;
  const int lrow = ln & 15, kg = ln >> 4;
  const int tbase = blockIdx.x * 64 + wv * 16;
  const int ar = min(tbase + lrow, NN - 1);

  f32x4 acc[8];
#pragma unroll
  for (int cf = 0; cf < 8; ++cf) acc[cf] = (f32x4){0.f, 0.f, 0.f, 0.f};
#pragma unroll
  for (int ks = 0; ks < 4; ++ks) {
    const s16x8 g0 = *reinterpret_cast<const s16x8*>(agg + (size_t)ar * 128 + ks * 32 + kg * 8);
    const s16x8 h0 = *reinterpret_cast<const s16x8*>(hb + (size_t)ar * 128 + ks * 32 + kg * 8);
#pragma unroll
    for (int cf = 0; cf < 8; ++cf) {
      const s16x8 bwl = *reinterpret_cast<const s16x8*>(WTl + (size_t)(cf * 16 + lrow) * 128 + ks * 32 + kg * 8);
      const s16x8 bwr = *reinterpret_cast<const s16x8*>(WTr + (size_t)(cf * 16 + lrow) * 128 + ks * 32 + kg * 8);
      acc[cf] = __builtin_amdgcn_mfma_f32_16x16x32_bf16(g0, bwl, acc[cf], 0, 0, 0);
      acc[cf] = __builtin_amdgcn_mfma_f32_16x16x32_bf16(h0, bwr, acc[cf], 0, 0, 0);
    }
  }

  float bb[8], gm[8], gb[8];
#pragma unroll
  for (int cf = 0; cf < 8; ++cf) {
    const int c = cf * 16 + lrow;
    bb[cf] = bl[c];
    gm[cf] = lg[c];
    gb[cf] = lb[c];
  }
#pragma unroll
  for (int j = 0; j < 4; ++j) {
    const int r = tbase + kg * 4 + j;
    const int rs = r < NN ? r : NN - 1;
    float v[8];
#pragma unroll
    for (int cf = 0; cf < 8; ++cf) {
      const int c = cf * 16 + lrow;
      v[cf] = b2f(hb[(size_t)rs * 128 + c]) + fmaxf(acc[cf][j] + bb[cf], 0.0f);
    }
    float s = 0.f;
#pragma unroll
    for (int cf = 0; cf < 8; ++cf) s += v[cf];
    s += __shfl_xor(s, 1); s += __shfl_xor(s, 2);
    s += __shfl_xor(s, 4); s += __shfl_xor(s, 8);
    const float mu = s * (1.0f / 128);
    float q = 0.f;
#pragma unroll
    for (int cf = 0; cf < 8; ++cf) { const float d = v[cf] - mu; q += d * d; }
    q += __shfl_xor(q, 1); q += __shfl_xor(q, 2);
    q += __shfl_xor(q, 4); q += __shfl_xor(q, 8);
    const float istd = rsqrtf(q * (1.0f / 128) + 1e-5f);
    if (r < NN) {
#pragma unroll
      for (int cf = 0; cf < 8; ++cf)
        hb_out[(size_t)r * 128 + cf * 16 + lrow] = f2b((v[cf] - mu) * istd * gm[cf] + gb[cf]);
    }
  }
}

// ---------------- SAGE layer 1 + classifier fused ----------------
__global__ __launch_bounds__(256) void k_sage_cls(
    const u16* __restrict__ agg, const u16* __restrict__ hb,
    const u16* __restrict__ WTl, const u16* __restrict__ WTr,
    const float* __restrict__ bl, const float* __restrict__ lg,
    const float* __restrict__ lb,
    const u16* __restrict__ Wc1, const float* __restrict__ cb1,
    const u16* __restrict__ Wc2, const float* __restrict__ cb2,
    float* __restrict__ out_h, float* __restrict__ logits) {
  __shared__ u16 th[64][136];
  const int tid = threadIdx.x;
  const int wv = tid >> 6, ln = tid & 63;
  const int lrow = ln & 15, kg = ln >> 4;
  const int tbase = blockIdx.x * 64 + wv * 16;
  const int lb0 = wv * 16;
  const int ar = min(tbase + lrow, NN - 1);

  f32x4 acc[8];
#pragma unroll
  for (int cf = 0; cf < 8; ++cf) acc[cf] = (f32x4){0.f, 0.f, 0.f, 0.f};
#pragma unroll
  for (int ks = 0; ks < 4; ++ks) {
    const s16x8 g0 = *reinterpret_cast<const s16x8*>(agg + (size_t)ar * 128 + ks * 32 + kg * 8);
    const s16x8 h0 = *reinterpret_cast<const s16x8*>(hb + (size_t)ar * 128 + ks * 32 + kg * 8);
#pragma unroll
    for (int cf = 0; cf < 8; ++cf) {
      const s16x8 bwl = *reinterpret_cast<const s16x8*>(WTl + (size_t)(cf * 16 + lrow) * 128 + ks * 32 + kg * 8);
      const s16x8 bwr = *reinterpret_cast<const s16x8*>(WTr + (size_t)(cf * 16 + lrow) * 128 + ks * 32 + kg * 8);
      acc[cf] = __builtin_amdgcn_mfma_f32_16x16x32_bf16(g0, bwl, acc[cf], 0, 0, 0);
      acc[cf] = __builtin_amdgcn_mfma_f32_16x16x32_bf16(h0, bwr, acc[cf], 0, 0, 0);
    }
  }

  {
    float bb[8], gm[8], gb[8];
#pragma unroll
    for (int cf = 0; cf < 8; ++cf) {
      const int c = cf * 16 + lrow;
      bb[cf] = bl[c];
      gm[cf] = lg[c];
      gb[cf] = lb[c];
    }
#pragma unroll
    for (int j = 0; j < 4; ++j) {
      const int r = tbase + kg * 4 + j;
      const int rs = r < NN ? r : NN - 1;
      const int lr = lb0 + kg * 4 + j;
      float v[8];
#pragma unroll
      for (int cf = 0; cf < 8; ++cf) {
        const int c = cf * 16 + lrow;
        v[cf] = b2f(hb[(size_t)rs * 128 + c]) + fmaxf(acc[cf][j] + bb[cf], 0.0f);
      }
      float s = 0.f;
#pragma unroll
      for (int cf = 0; cf < 8; ++cf) s += v[cf];
      s += __shfl_xor(s, 1); s += __shfl_xor(s, 2);
      s += __shfl_xor(s, 4); s += __shfl_xor(s, 8);
      const float mu = s * (1.0f / 128);
      float q = 0.f;
#pragma unroll
      for (int cf = 0; cf < 8; ++cf) { const float d = v[cf] - mu; q += d * d; }
      q += __shfl_xor(q, 1); q += __shfl_xor(q, 2);
      q += __shfl_xor(q, 4); q += __shfl_xor(q, 8);
      const float istd = rsqrtf(q * (1.0f / 128) + 1e-5f);
#pragma unroll
      for (int cf = 0; cf < 8; ++cf) {
        const int c = cf * 16 + lrow;
        const float o = (v[cf] - mu) * istd * gm[cf] + gb[cf];
        th[lr][c] = f2b(o);
        if (r < NN) out_h[(size_t)r * 128 + c] = o;
      }
    }
  }
  __syncthreads();

  // classifier: wave-private 16-row tile
  float cb1v[8];
#pragma unroll
  for (int cf = 0; cf < 8; ++cf) cb1v[cf] = cb1[cf * 16 + lrow];

  f32x4 a3[8];
#pragma unroll
  for (int cf = 0; cf < 8; ++cf) a3[cf] = (f32x4){0.f, 0.f, 0.f, 0.f};
#pragma unroll
  for (int ks = 0; ks < 4; ++ks) {
    const s16x8 a = *reinterpret_cast<const s16x8*>(&th[lb0 + lrow][ks * 32 + kg * 8]);
#pragma unroll
    for (int cf = 0; cf < 8; ++cf) {
      const s16x8 bf = *reinterpret_cast<const s16x8*>(Wc1 + (size_t)(cf * 16 + lrow) * 128 + ks * 32 + kg * 8);
      a3[cf] = __builtin_amdgcn_mfma_f32_16x16x32_bf16(a, bf, a3[cf], 0, 0, 0);
    }
  }
#pragma unroll
  for (int j = 0; j < 4; ++j)
#pragma unroll
    for (int cf = 0; cf < 8; ++cf)
      th[lb0 + kg * 4 + j][cf * 16 + lrow] = f2b(fmaxf(a3[cf][j] + cb1v[cf], 0.0f));
  __syncthreads();

  f32x4 a2[3];
#pragma unroll
  for (int cf = 0; cf < 3; ++cf) a2[cf] = (f32x4){0.f, 0.f, 0.f, 0.f};
#pragma unroll
  for (int ks = 0; ks < 4; ++ks) {
    const s16x8 a = *reinterpret_cast<const s16x8*>(&th[lb0 + lrow][ks * 32 + kg * 8]);
#pragma unroll
    for (int cf = 0; cf < 3; ++cf) {
      const int bn = min(cf * 16 + lrow, CC - 1);
      const s16x8 bf = *reinterpret_cast<const s16x8*>(Wc2 + (size_t)bn * 128 + ks * 32 + kg * 8);
      a2[cf] = __builtin_amdgcn_mfma_f32_16x16x32_bf16(a, bf, a2[cf], 0, 0, 0);
    }
  }
#pragma unroll
  for (int j = 0; j < 4; ++j) {
    const int r = tbase + kg * 4 + j;
    if (r < NN) {
#pragma unroll
      for (int cf = 0; cf < 3; ++cf) {
        const int c = cf * 16 + lrow;
        if (c < CC) logits[(size_t)r * CC + c] = a2[cf][j] + cb2[c];
      }
    }
  }
}

}  // namespace

extern "C" void kernel_launch(void* const* d_in, const int* in_sizes, int n_in,
                              void* d_out, int out_size, void* d_ws, size_t ws_size,
                              hipStream_t stream) {
  (void)in_sizes; (void)n_in; (void)out_size; (void)ws_size;
  const float* x   = (const float*)d_in[0];
  const int*   ei  = (const int*)d_in[1];
  const float* pw1 = (const float*)d_in[2];
  const float* pb1 = (const float*)d_in[3];
  const float* pw2 = (const float*)d_in[4];
  const float* pb2 = (const float*)d_in[5];
  const float* ing = (const float*)d_in[6];
  const float* inb = (const float*)d_in[7];
  const float* swl = (const float*)d_in[8];
  const float* sbl = (const float*)d_in[9];
  const float* swr = (const float*)d_in[10];
  const float* lng = (const float*)d_in[11];
  const float* lnb = (const float*)d_in[12];
  const float* cw1 = (const float*)d_in[13];
  const float* cb1 = (const float*)d_in[14];
  const float* cw2 = (const float*)d_in[15];
  const float* cb2 = (const float*)d_in[16];

  float* out_logits = (float*)d_out;
  float* out_h = out_logits + (size_t)NN * CC;

  const size_t NNH = (size_t)NN * HH;
  u16*   hb   = (u16*)d_ws;                // 12.8 MB
  u16*   bufA = hb + NNH;                  // 12.8 MB (agg)
  u16*   wt   = bufA + NNH;                // 256 KB
  int*   cnt    = (int*)(wt + 8 * 16384);  // NN
  int*   cursor = cnt + NN;                // NN (adjacent: single memset)
  float* inv    = (float*)(cursor + NN);   // NN
  int*   rowptr = (int*)(inv + NN);        // NN+1
  int*   bsum   = rowptr + NN + 1;         // 256
  int*   colarr = bsum + 256;              // EE

  // ---- CSR build ----
  hipMemsetAsync(cnt, 0, 2 * NN * sizeof(int), stream);
  k_degree<<<(EE + 255) / 256, 256, 0, stream>>>(ei, cnt);
  k_scan_block<<<SCAN_NB, 256, 0, stream>>>(cnt, rowptr, bsum, inv);
  k_scan_tops<<<1, 256, 0, stream>>>(bsum);
  k_scan_add<<<SCAN_NB, 256, 0, stream>>>(rowptr, bsum);
  k_fill<<<(EE + 255) / 256, 256, 0, stream>>>(ei, rowptr, cursor, colarr);
  k_prep_w<<<(7 * 16384 + CC * 128 + 255) / 256, 256, 0, stream>>>(
      pw1, pw2, swl, swr, cw1, cw2, wt);

  const int MG = (NN + 63) / 64;  // 782
  // h = LN(relu(x@pw1+pb1)@pw2+pb2)   -> hb
  k_mlp<<<MG, 256, 0, stream>>>(x, wt + 0 * 16384, pb1, wt + 1 * 16384, pb2, ing, inb, hb);

  // layer 0
  k_gather_q<<<(NN + 15) / 16, 256, 0, stream>>>(hb, rowptr, colarr, inv, bufA);
  k_sage0<<<MG, 256, 0, stream>>>(
      bufA, hb, wt + 2 * 16384, wt + 4 * 16384, sbl, lng, lnb, hb);

  // layer 1 + classifier
  k_gather_q<<<(NN + 15) / 16, 256, 0, stream>>>(hb, rowptr, colarr, inv, bufA);
  k_sage_cls<<<MG, 256, 0, stream>>>(
      bufA, hb, wt + 3 * 16384, wt + 5 * 16384, sbl + HH, lng + HH, lnb + HH,
      wt + 6 * 16384, cb1, wt + 7 * 16384, cb2, out_h, out_logits);
}

// Round 8
// 186.568 us; speedup vs baseline: 1.4268x; 1.4268x over previous
//
#include <hip/hip_runtime.h>

// GNN encoder: input MLP + LN, 2x SAGEConv(mean) + ReLU + residual + LN, classifier MLP.
// Round 8: dense kernels latency fix — weights staged in LDS once per block
// (XOR-swizzled, conflict-free ds_read_b128 fragments), 128 rows/block, 2 row-tiles/wave.
//  - k_mlp:      LDS = WT1(32K) | t1-tile(32K); WT2 re-staged over WT1
//  - k_sage0:    LDS = WTl(32K) | WTr(32K)
//  - k_sage_cls: LDS = WTl | WTr | Wc2(10K); th-tile over WTl, Wc1 over WTr after barrier
//  - gather: quarter-wave per node; CSR: multi-block hierarchical scan

namespace {

constexpr int NN = 50000;
constexpr int EE = 640000;
constexpr int HH = 128;
constexpr int CC = 40;
constexpr int SCAN_NB = (NN + 255) / 256;  // 196

typedef unsigned short u16;
typedef __attribute__((ext_vector_type(8))) short s16x8;
typedef __attribute__((ext_vector_type(8))) unsigned short u16x8;
typedef __attribute__((ext_vector_type(4))) float f32x4;

__device__ __forceinline__ float b2f(u16 h) {
  unsigned int u = ((unsigned int)h) << 16;
  return __builtin_bit_cast(float, u);
}
__device__ __forceinline__ u16 f2b(float f) {
  unsigned int u = __builtin_bit_cast(unsigned int, f);
  u += 0x7FFFu + ((u >> 16) & 1u);
  return (u16)(u >> 16);
}

// ---- swizzled LDS tile helpers: row n (0..127), 16B-granule k0 (0..15) ----
// slot = k0 ^ (n & 15): 16-lane reads at row-stride hit 8 bank-groups 2-way (free).
__device__ __forceinline__ s16x8 ldsw(const u16* base, int n, int k0) {
  return *reinterpret_cast<const s16x8*>(base + n * 128 + (((k0 ^ n) & 15) << 3));
}
__device__ __forceinline__ void stsw(u16* base, int r, int c, u16 v) {
  base[r * 128 + ((((c >> 3) ^ r) & 15) << 3) + (c & 7)] = v;
}
// cooperative stage: NGRAN 16B-granules from linear src -> swizzled dst
template <int NGRAN>
__device__ __forceinline__ void stage(const u16* __restrict__ src, u16* dst, int tid) {
#pragma unroll
  for (int i = 0; i < (NGRAN + 255) / 256; ++i) {
    const int gi = i * 256 + tid;
    if ((NGRAN & 255) == 0 || gi < NGRAN) {
      const int n = gi >> 4, k0 = gi & 15;
      const u16x8 v = *reinterpret_cast<const u16x8*>(src + gi * 8);
      *reinterpret_cast<u16x8*>(dst + n * 128 + (((k0 ^ n) & 15) << 3)) = v;
    }
  }
}

// ---------------- CSR build ----------------
__global__ void k_degree(const int* __restrict__ ei, int* __restrict__ cnt) {
  int e = blockIdx.x * 256 + threadIdx.x;
  if (e < EE) atomicAdd(&cnt[ei[EE + e]], 1);
}

__global__ void k_scan_block(const int* __restrict__ cnt, int* __restrict__ rowptr,
                             int* __restrict__ bsum, float* __restrict__ inv) {
  __shared__ int s[256];
  const int t = threadIdx.x;
  const int i = blockIdx.x * 256 + t;
  const int v = i < NN ? cnt[i] : 0;
  s[t] = v;
  __syncthreads();
  for (int off = 1; off < 256; off <<= 1) {
    int add = t >= off ? s[t - off] : 0;
    __syncthreads();
    s[t] += add;
    __syncthreads();
  }
  if (i < NN) {
    rowptr[i] = s[t] - v;
    inv[i] = v > 0 ? 1.0f / (float)v : 0.0f;
  }
  if (t == 255) bsum[blockIdx.x] = s[255];
}

__global__ void k_scan_tops(int* __restrict__ bsum) {
  __shared__ int s[256];
  const int t = threadIdx.x;
  const int v = t < SCAN_NB ? bsum[t] : 0;
  s[t] = v;
  __syncthreads();
  for (int off = 1; off < 256; off <<= 1) {
    int add = t >= off ? s[t - off] : 0;
    __syncthreads();
    s[t] += add;
    __syncthreads();
  }
  if (t < SCAN_NB) bsum[t] = s[t] - v;
}

__global__ void k_scan_add(int* __restrict__ rowptr, const int* __restrict__ bsum) {
  const int i = blockIdx.x * 256 + threadIdx.x;
  if (i < NN) rowptr[i] += bsum[blockIdx.x];
  if (i == 0) rowptr[NN] = EE;
}

__global__ void k_fill(const int* __restrict__ ei, const int* __restrict__ rowptr,
                       int* __restrict__ cursor, int* __restrict__ col) {
  int e = blockIdx.x * 256 + threadIdx.x;
  if (e >= EE) return;
  int s = ei[e];
  int d = ei[EE + e];
  int pos = atomicAdd(&cursor[d], 1);
  col[rowptr[d] + pos] = s;
}

// transpose+cast all weights into wt slots {pw1,pw2,wl0,wl1,wr0,wr1,cw1,cw2T}
__global__ void k_prep_w(const float* __restrict__ pw1, const float* __restrict__ pw2,
                         const float* __restrict__ swl, const float* __restrict__ swr,
                         const float* __restrict__ cw1, const float* __restrict__ cw2,
                         u16* __restrict__ wt) {
  int flat = blockIdx.x * 256 + threadIdx.x;
  const int SEVEN = 7 * 16384;
  if (flat < SEVEN) {
    int id = flat >> 14;
    int off = flat & 16383;
    int n = off >> 7, k = off & 127;
    const float* s;
    switch (id) {
      case 0: s = pw1; break;
      case 1: s = pw2; break;
      case 2: s = swl; break;
      case 3: s = swl + 16384; break;
      case 4: s = swr; break;
      case 5: s = swr + 16384; break;
      default: s = cw1; break;
    }
    wt[(size_t)id * 16384 + n * 128 + k] = f2b(s[k * 128 + n]);
  } else {
    int off = flat - SEVEN;
    if (off < CC * 128) {
      int n = off >> 7, k = off & 127;
      wt[(size_t)7 * 16384 + n * 128 + k] = f2b(cw2[k * CC + n]);
    }
  }
}

// ---------------- aggregation: quarter-wave per node, 4 edges in flight ----------------
__global__ __launch_bounds__(256) void k_gather_q(
    const u16* __restrict__ hb, const int* __restrict__ rowptr,
    const int* __restrict__ col, const float* __restrict__ inv,
    u16* __restrict__ agg) {
  const int tid = threadIdx.x;
  const int node = blockIdx.x * 16 + (tid >> 4);
  if (node >= NN) return;
  const int ln = tid & 15;
  const int cl = ln * 8;
  const int start = rowptr[node];
  const int end = rowptr[node + 1];
  float a[8] = {0.f, 0.f, 0.f, 0.f, 0.f, 0.f, 0.f, 0.f};
  int i = start;
  for (; i + 4 <= end; i += 4) {
    const int s0 = col[i], s1 = col[i + 1], s2 = col[i + 2], s3 = col[i + 3];
    const u16x8 v0 = *reinterpret_cast<const u16x8*>(&hb[(size_t)s0 * HH + cl]);
    const u16x8 v1 = *reinterpret_cast<const u16x8*>(&hb[(size_t)s1 * HH + cl]);
    const u16x8 v2 = *reinterpret_cast<const u16x8*>(&hb[(size_t)s2 * HH + cl]);
    const u16x8 v3 = *reinterpret_cast<const u16x8*>(&hb[(size_t)s3 * HH + cl]);
#pragma unroll
    for (int k = 0; k < 8; ++k)
      a[k] += (b2f(v0[k]) + b2f(v1[k])) + (b2f(v2[k]) + b2f(v3[k]));
  }
  for (; i < end; ++i) {
    const int s0 = col[i];
    const u16x8 v0 = *reinterpret_cast<const u16x8*>(&hb[(size_t)s0 * HH + cl]);
#pragma unroll
    for (int k = 0; k < 8; ++k) a[k] += b2f(v0[k]);
  }
  const float sc = inv[node];
  u16x8 o;
#pragma unroll
  for (int k = 0; k < 8; ++k) o[k] = f2b(a[k] * sc);
  *reinterpret_cast<u16x8*>(&agg[(size_t)node * HH + cl]) = o;
}

// ---------------- fused input MLP: h = LN(relu(x@pw1+pb1)@pw2+pb2) ----------------
// LDS: [0,16384) = W (WT1 then WT2), [16384,32768) = t1 tile (128x128 swizzled)
__global__ __launch_bounds__(256) void k_mlp(
    const float* __restrict__ x, const u16* __restrict__ WT1,
    const float* __restrict__ pb1, const u16* __restrict__ WT2,
    const float* __restrict__ pb2, const float* __restrict__ lg,
    const float* __restrict__ lb, u16* __restrict__ hb) {
  __shared__ u16 lds[32768];
  u16* wreg = lds;
  u16* t1r = lds + 16384;
  const int tid = threadIdx.x;
  const int wv = tid >> 6, ln = tid & 63;
  const int lrow = ln & 15, kg = ln >> 4;
  const int tbase = blockIdx.x * 128 + wv * 32;
  const int lb0 = wv * 32;
  const int ar0 = min(tbase + lrow, NN - 1);
  const int ar1 = min(tbase + 16 + lrow, NN - 1);

  stage<2048>(WT1, wreg, tid);
  __syncthreads();

  f32x4 acc0[8], acc1[8];
#pragma unroll
  for (int cf = 0; cf < 8; ++cf) {
    acc0[cf] = (f32x4){0.f, 0.f, 0.f, 0.f};
    acc1[cf] = (f32x4){0.f, 0.f, 0.f, 0.f};
  }
#pragma unroll
  for (int ks = 0; ks < 4; ++ks) {
    const float4* p0 = reinterpret_cast<const float4*>(x + (size_t)ar0 * 128 + ks * 32 + kg * 8);
    const float4* p1 = reinterpret_cast<const float4*>(x + (size_t)ar1 * 128 + ks * 32 + kg * 8);
    float4 x0 = p0[0], x1 = p0[1], y0 = p1[0], y1 = p1[1];
    s16x8 a0, a1;
    a0[0] = (short)f2b(x0.x); a0[1] = (short)f2b(x0.y); a0[2] = (short)f2b(x0.z); a0[3] = (short)f2b(x0.w);
    a0[4] = (short)f2b(x1.x); a0[5] = (short)f2b(x1.y); a0[6] = (short)f2b(x1.z); a0[7] = (short)f2b(x1.w);
    a1[0] = (short)f2b(y0.x); a1[1] = (short)f2b(y0.y); a1[2] = (short)f2b(y0.z); a1[3] = (short)f2b(y0.w);
    a1[4] = (short)f2b(y1.x); a1[5] = (short)f2b(y1.y); a1[6] = (short)f2b(y1.z); a1[7] = (short)f2b(y1.w);
#pragma unroll
    for (int cf = 0; cf < 8; ++cf) {
      const s16x8 bf = ldsw(wreg, cf * 16 + lrow, ks * 4 + kg);
      acc0[cf] = __builtin_amdgcn_mfma_f32_16x16x32_bf16(a0, bf, acc0[cf], 0, 0, 0);
      acc1[cf] = __builtin_amdgcn_mfma_f32_16x16x32_bf16(a1, bf, acc1[cf], 0, 0, 0);
    }
  }
  {
    float bb[8];
#pragma unroll
    for (int cf = 0; cf < 8; ++cf) bb[cf] = pb1[cf * 16 + lrow];
#pragma unroll
    for (int t = 0; t < 2; ++t)
#pragma unroll
      for (int j = 0; j < 4; ++j) {
        const int lr = lb0 + t * 16 + kg * 4 + j;
#pragma unroll
        for (int cf = 0; cf < 8; ++cf)
          stsw(t1r, lr, cf * 16 + lrow, f2b(fmaxf((t ? acc1[cf][j] : acc0[cf][j]) + bb[cf], 0.0f)));
      }
  }
  __syncthreads();           // WT1 reads + t1 writes done
  stage<2048>(WT2, wreg, tid);
  __syncthreads();

  // phase 2: h = LN(t1 @ pw2 + pb2)
  f32x4 c0[8], c1[8];
#pragma unroll
  for (int cf = 0; cf < 8; ++cf) {
    c0[cf] = (f32x4){0.f, 0.f, 0.f, 0.f};
    c1[cf] = (f32x4){0.f, 0.f, 0.f, 0.f};
  }
#pragma unroll
  for (int ks = 0; ks < 4; ++ks) {
    const s16x8 a0 = ldsw(t1r, lb0 + lrow, ks * 4 + kg);
    const s16x8 a1 = ldsw(t1r, lb0 + 16 + lrow, ks * 4 + kg);
#pragma unroll
    for (int cf = 0; cf < 8; ++cf) {
      const s16x8 bf = ldsw(wreg, cf * 16 + lrow, ks * 4 + kg);
      c0[cf] = __builtin_amdgcn_mfma_f32_16x16x32_bf16(a0, bf, c0[cf], 0, 0, 0);
      c1[cf] = __builtin_amdgcn_mfma_f32_16x16x32_bf16(a1, bf, c1[cf], 0, 0, 0);
    }
  }

  float bb[8], gm[8], gb[8];
#pragma unroll
  for (int cf = 0; cf < 8; ++cf) {
    const int c = cf * 16 + lrow;
    bb[cf] = pb2[c];
    gm[cf] = lg[c];
    gb[cf] = lb[c];
  }
#pragma unroll
  for (int t = 0; t < 2; ++t)
#pragma unroll
    for (int j = 0; j < 4; ++j) {
      const int r = tbase + t * 16 + kg * 4 + j;
      float v[8];
#pragma unroll
      for (int cf = 0; cf < 8; ++cf) v[cf] = (t ? c1[cf][j] : c0[cf][j]) + bb[cf];
      float s = 0.f;
#pragma unroll
      for (int cf = 0; cf < 8; ++cf) s += v[cf];
      s += __shfl_xor(s, 1); s += __shfl_xor(s, 2);
      s += __shfl_xor(s, 4); s += __shfl_xor(s, 8);
      const float mu = s * (1.0f / 128);
      float q = 0.f;
#pragma unroll
      for (int cf = 0; cf < 8; ++cf) { const float d = v[cf] - mu; q += d * d; }
      q += __shfl_xor(q, 1); q += __shfl_xor(q, 2);
      q += __shfl_xor(q, 4); q += __shfl_xor(q, 8);
      const float istd = rsqrtf(q * (1.0f / 128) + 1e-5f);
      if (r < NN) {
#pragma unroll
        for (int cf = 0; cf < 8; ++cf)
          hb[(size_t)r * 128 + cf * 16 + lrow] = f2b((v[cf] - mu) * istd * gm[cf] + gb[cf]);
      }
    }
}

// ---------------- SAGE layer 0: h' = LN(h + relu(agg@WL + bl + h@WR)) -> hb ----------------
__global__ __launch_bounds__(256) void k_sage0(
    const u16* __restrict__ agg, const u16* __restrict__ hb,
    const u16* __restrict__ WTl, const u16* __restrict__ WTr,
    const float* __restrict__ bl, const float* __restrict__ lg,
    const float* __restrict__ lb, u16* __restrict__ hb_out) {
  __shared__ u16 lds[32768];
  u16* wl = lds;
  u16* wr = lds + 16384;
  const int tid = threadIdx.x;
  const int wv = tid >> 6, ln = tid & 63;
  const int lrow = ln & 15, kg = ln >> 4;
  const int tbase = blockIdx.x * 128 + wv * 32;
  const int ar0 = min(tbase + lrow, NN - 1);
  const int ar1 = min(tbase + 16 + lrow, NN - 1);

  stage<2048>(WTl, wl, tid);
  stage<2048>(WTr, wr, tid);
  __syncthreads();

  f32x4 acc0[8], acc1[8];
#pragma unroll
  for (int cf = 0; cf < 8; ++cf) {
    acc0[cf] = (f32x4){0.f, 0.f, 0.f, 0.f};
    acc1[cf] = (f32x4){0.f, 0.f, 0.f, 0.f};
  }
#pragma unroll
  for (int ks = 0; ks < 4; ++ks) {
    const s16x8 g0 = *reinterpret_cast<const s16x8*>(agg + (size_t)ar0 * 128 + ks * 32 + kg * 8);
    const s16x8 g1 = *reinterpret_cast<const s16x8*>(agg + (size_t)ar1 * 128 + ks * 32 + kg * 8);
    const s16x8 h0 = *reinterpret_cast<const s16x8*>(hb + (size_t)ar0 * 128 + ks * 32 + kg * 8);
    const s16x8 h1 = *reinterpret_cast<const s16x8*>(hb + (size_t)ar1 * 128 + ks * 32 + kg * 8);
#pragma unroll
    for (int cf = 0; cf < 8; ++cf) {
      const s16x8 bwl = ldsw(wl, cf * 16 + lrow, ks * 4 + kg);
      const s16x8 bwr = ldsw(wr, cf * 16 + lrow, ks * 4 + kg);
      acc0[cf] = __builtin_amdgcn_mfma_f32_16x16x32_bf16(g0, bwl, acc0[cf], 0, 0, 0);
      acc0[cf] = __builtin_amdgcn_mfma_f32_16x16x32_bf16(h0, bwr, acc0[cf], 0, 0, 0);
      acc1[cf] = __builtin_amdgcn_mfma_f32_16x16x32_bf16(g1, bwl, acc1[cf], 0, 0, 0);
      acc1[cf] = __builtin_amdgcn_mfma_f32_16x16x32_bf16(h1, bwr, acc1[cf], 0, 0, 0);
    }
  }

  float bb[8], gm[8], gb[8];
#pragma unroll
  for (int cf = 0; cf < 8; ++cf) {
    const int c = cf * 16 + lrow;
    bb[cf] = bl[c];
    gm[cf] = lg[c];
    gb[cf] = lb[c];
  }
#pragma unroll
  for (int t = 0; t < 2; ++t)
#pragma unroll
    for (int j = 0; j < 4; ++j) {
      const int r = tbase + t * 16 + kg * 4 + j;
      const int rs = r < NN ? r : NN - 1;
      float v[8];
#pragma unroll
      for (int cf = 0; cf < 8; ++cf) {
        const int c = cf * 16 + lrow;
        v[cf] = b2f(hb[(size_t)rs * 128 + c]) +
                fmaxf((t ? acc1[cf][j] : acc0[cf][j]) + bb[cf], 0.0f);
      }
      float s = 0.f;
#pragma unroll
      for (int cf = 0; cf < 8; ++cf) s += v[cf];
      s += __shfl_xor(s, 1); s += __shfl_xor(s, 2);
      s += __shfl_xor(s, 4); s += __shfl_xor(s, 8);
      const float mu = s * (1.0f / 128);
      float q = 0.f;
#pragma unroll
      for (int cf = 0; cf < 8; ++cf) { const float d = v[cf] - mu; q += d * d; }
      q += __shfl_xor(q, 1); q += __shfl_xor(q, 2);
      q += __shfl_xor(q, 4); q += __shfl_xor(q, 8);
      const float istd = rsqrtf(q * (1.0f / 128) + 1e-5f);
      if (r < NN) {
#pragma unroll
        for (int cf = 0; cf < 8; ++cf)
          hb_out[(size_t)r * 128 + cf * 16 + lrow] = f2b((v[cf] - mu) * istd * gm[cf] + gb[cf]);
      }
    }
}

// ---------------- SAGE layer 1 + classifier fused ----------------
// LDS: [0,16384)=WTl -> th tile; [16384,32768)=WTr -> Wc1; [32768,37888)=Wc2
__global__ __launch_bounds__(256) void k_sage_cls(
    const u16* __restrict__ agg, const u16* __restrict__ hb,
    const u16* __restrict__ WTl, const u16* __restrict__ WTr,
    const float* __restrict__ bl, const float* __restrict__ lg,
    const float* __restrict__ lb,
    const u16* __restrict__ Wc1, const float* __restrict__ cb1,
    const u16* __restrict__ Wc2, const float* __restrict__ cb2,
    float* __restrict__ out_h, float* __restrict__ logits) {
  __shared__ u16 lds[37888];
  u16* wl = lds;          // phase A: WTl ; phase B: th tile (128x128)
  u16* wr = lds + 16384;  // phase A: WTr ; phase B: Wc1
  u16* w2 = lds + 32768;  // Wc2 (40x128)
  const int tid = threadIdx.x;
  const int wv = tid >> 6, ln = tid & 63;
  const int lrow = ln & 15, kg = ln >> 4;
  const int tbase = blockIdx.x * 128 + wv * 32;
  const int lb0 = wv * 32;
  const int ar0 = min(tbase + lrow, NN - 1);
  const int ar1 = min(tbase + 16 + lrow, NN - 1);

  stage<2048>(WTl, wl, tid);
  stage<2048>(WTr, wr, tid);
  stage<640>(Wc2, w2, tid);
  __syncthreads();

  f32x4 acc0[8], acc1[8];
#pragma unroll
  for (int cf = 0; cf < 8; ++cf) {
    acc0[cf] = (f32x4){0.f, 0.f, 0.f, 0.f};
    acc1[cf] = (f32x4){0.f, 0.f, 0.f, 0.f};
  }
#pragma unroll
  for (int ks = 0; ks < 4; ++ks) {
    const s16x8 g0 = *reinterpret_cast<const s16x8*>(agg + (size_t)ar0 * 128 + ks * 32 + kg * 8);
    const s16x8 g1 = *reinterpret_cast<const s16x8*>(agg + (size_t)ar1 * 128 + ks * 32 + kg * 8);
    const s16x8 h0 = *reinterpret_cast<const s16x8*>(hb + (size_t)ar0 * 128 + ks * 32 + kg * 8);
    const s16x8 h1 = *reinterpret_cast<const s16x8*>(hb + (size_t)ar1 * 128 + ks * 32 + kg * 8);
#pragma unroll
    for (int cf = 0; cf < 8; ++cf) {
      const s16x8 bwl = ldsw(wl, cf * 16 + lrow, ks * 4 + kg);
      const s16x8 bwr = ldsw(wr, cf * 16 + lrow, ks * 4 + kg);
      acc0[cf] = __builtin_amdgcn_mfma_f32_16x16x32_bf16(g0, bwl, acc0[cf], 0, 0, 0);
      acc0[cf] = __builtin_amdgcn_mfma_f32_16x16x32_bf16(h0, bwr, acc0[cf], 0, 0, 0);
      acc1[cf] = __builtin_amdgcn_mfma_f32_16x16x32_bf16(g1, bwl, acc1[cf], 0, 0, 0);
      acc1[cf] = __builtin_amdgcn_mfma_f32_16x16x32_bf16(h1, bwr, acc1[cf], 0, 0, 0);
    }
  }
  __syncthreads();  // all waves done reading WTl/WTr

  {
    float bb[8], gm[8], gb[8];
#pragma unroll
    for (int cf = 0; cf < 8; ++cf) {
      const int c = cf * 16 + lrow;
      bb[cf] = bl[c];
      gm[cf] = lg[c];
      gb[cf] = lb[c];
    }
#pragma unroll
    for (int t = 0; t < 2; ++t)
#pragma unroll
      for (int j = 0; j < 4; ++j) {
        const int r = tbase + t * 16 + kg * 4 + j;
        const int rs = r < NN ? r : NN - 1;
        const int lr = lb0 + t * 16 + kg * 4 + j;
        float v[8];
#pragma unroll
        for (int cf = 0; cf < 8; ++cf) {
          const int c = cf * 16 + lrow;
          v[cf] = b2f(hb[(size_t)rs * 128 + c]) +
                  fmaxf((t ? acc1[cf][j] : acc0[cf][j]) + bb[cf], 0.0f);
        }
        float s = 0.f;
#pragma unroll
        for (int cf = 0; cf < 8; ++cf) s += v[cf];
        s += __shfl_xor(s, 1); s += __shfl_xor(s, 2);
        s += __shfl_xor(s, 4); s += __shfl_xor(s, 8);
        const float mu = s * (1.0f / 128);
        float q = 0.f;
#pragma unroll
        for (int cf = 0; cf < 8; ++cf) { const float d = v[cf] - mu; q += d * d; }
        q += __shfl_xor(q, 1); q += __shfl_xor(q, 2);
        q += __shfl_xor(q, 4); q += __shfl_xor(q, 8);
        const float istd = rsqrtf(q * (1.0f / 128) + 1e-5f);
#pragma unroll
        for (int cf = 0; cf < 8; ++cf) {
          const int c = cf * 16 + lrow;
          const float o = (v[cf] - mu) * istd * gm[cf] + gb[cf];
          stsw(wl, lr, c, f2b(o));
          if (r < NN) out_h[(size_t)r * 128 + c] = o;
        }
      }
  }
  stage<2048>(Wc1, wr, tid);  // Wc1 over WTr (all reads done at barrier above)
  __syncthreads();

  // classifier: per wave, its own two 16-row th tiles
  float cb1v[8];
#pragma unroll
  for (int cf = 0; cf < 8; ++cf) cb1v[cf] = cb1[cf * 16 + lrow];

#pragma unroll
  for (int t = 0; t < 2; ++t) {
    const int rb = lb0 + t * 16;
    f32x4 a3[8];
#pragma unroll
    for (int cf = 0; cf < 8; ++cf) a3[cf] = (f32x4){0.f, 0.f, 0.f, 0.f};
#pragma unroll
    for (int ks = 0; ks < 4; ++ks) {
      const s16x8 a = ldsw(wl, rb + lrow, ks * 4 + kg);
#pragma unroll
      for (int cf = 0; cf < 8; ++cf) {
        const s16x8 bf = ldsw(wr, cf * 16 + lrow, ks * 4 + kg);
        a3[cf] = __builtin_amdgcn_mfma_f32_16x16x32_bf16(a, bf, a3[cf], 0, 0, 0);
      }
    }
    // t3 overwrites this wave's own th rows
#pragma unroll
    for (int j = 0; j < 4; ++j)
#pragma unroll
      for (int cf = 0; cf < 8; ++cf)
        stsw(wl, rb + kg * 4 + j, cf * 16 + lrow, f2b(fmaxf(a3[cf][j] + cb1v[cf], 0.0f)));

    f32x4 a2[3];
#pragma unroll
    for (int cf = 0; cf < 3; ++cf) a2[cf] = (f32x4){0.f, 0.f, 0.f, 0.f};
#pragma unroll
    for (int ks = 0; ks < 4; ++ks) {
      const s16x8 a = ldsw(wl, rb + lrow, ks * 4 + kg);
#pragma unroll
      for (int cf = 0; cf < 3; ++cf) {
        const int bn = min(cf * 16 + lrow, CC - 1);
        const s16x8 bf = ldsw(w2, bn, ks * 4 + kg);
        a2[cf] = __builtin_amdgcn_mfma_f32_16x16x32_bf16(a, bf, a2[cf], 0, 0, 0);
      }
    }
#pragma unroll
    for (int j = 0; j < 4; ++j) {
      const int r = tbase + t * 16 + kg * 4 + j;
      if (r < NN) {
#pragma unroll
        for (int cf = 0; cf < 3; ++cf) {
          const int c = cf * 16 + lrow;
          if (c < CC) logits[(size_t)r * CC + c] = a2[cf][j] + cb2[c];
        }
      }
    }
  }
}

}  // namespace

extern "C" void kernel_launch(void* const* d_in, const int* in_sizes, int n_in,
                              void* d_out, int out_size, void* d_ws, size_t ws_size,
                              hipStream_t stream) {
  (void)in_sizes; (void)n_in; (void)out_size; (void)ws_size;
  const float* x   = (const float*)d_in[0];
  const int*   ei  = (const int*)d_in[1];
  const float* pw1 = (const float*)d_in[2];
  const float* pb1 = (const float*)d_in[3];
  const float* pw2 = (const float*)d_in[4];
  const float* pb2 = (const float*)d_in[5];
  const float* ing = (const float*)d_in[6];
  const float* inb = (const float*)d_in[7];
  const float* swl = (const float*)d_in[8];
  const float* sbl = (const float*)d_in[9];
  const float* swr = (const float*)d_in[10];
  const float* lng = (const float*)d_in[11];
  const float* lnb = (const float*)d_in[12];
  const float* cw1 = (const float*)d_in[13];
  const float* cb1 = (const float*)d_in[14];
  const float* cw2 = (const float*)d_in[15];
  const float* cb2 = (const float*)d_in[16];

  float* out_logits = (float*)d_out;
  float* out_h = out_logits + (size_t)NN * CC;

  const size_t NNH = (size_t)NN * HH;
  u16*   hb   = (u16*)d_ws;                // 12.8 MB
  u16*   bufA = hb + NNH;                  // 12.8 MB (agg)
  u16*   wt   = bufA + NNH;                // 256 KB
  int*   cnt    = (int*)(wt + 8 * 16384);  // NN
  int*   cursor = cnt + NN;                // NN (adjacent: single memset)
  float* inv    = (float*)(cursor + NN);   // NN
  int*   rowptr = (int*)(inv + NN);        // NN+1
  int*   bsum   = rowptr + NN + 1;         // 256
  int*   colarr = bsum + 256;              // EE

  // ---- CSR build ----
  hipMemsetAsync(cnt, 0, 2 * NN * sizeof(int), stream);
  k_degree<<<(EE + 255) / 256, 256, 0, stream>>>(ei, cnt);
  k_scan_block<<<SCAN_NB, 256, 0, stream>>>(cnt, rowptr, bsum, inv);
  k_scan_tops<<<1, 256, 0, stream>>>(bsum);
  k_scan_add<<<SCAN_NB, 256, 0, stream>>>(rowptr, bsum);
  k_fill<<<(EE + 255) / 256, 256, 0, stream>>>(ei, rowptr, cursor, colarr);
  k_prep_w<<<(7 * 16384 + CC * 128 + 255) / 256, 256, 0, stream>>>(
      pw1, pw2, swl, swr, cw1, cw2, wt);

  const int MG = (NN + 127) / 128;  // 391
  // h = LN(relu(x@pw1+pb1)@pw2+pb2)   -> hb
  k_mlp<<<MG, 256, 0, stream>>>(x, wt + 0 * 16384, pb1, wt + 1 * 16384, pb2, ing, inb, hb);

  // layer 0
  k_gather_q<<<(NN + 15) / 16, 256, 0, stream>>>(hb, rowptr, colarr, inv, bufA);
  k_sage0<<<MG, 256, 0, stream>>>(
      bufA, hb, wt + 2 * 16384, wt + 4 * 16384, sbl, lng, lnb, hb);

  // layer 1 + classifier
  k_gather_q<<<(NN + 15) / 16, 256, 0, stream>>>(hb, rowptr, colarr, inv, bufA);
  k_sage_cls<<<MG, 256, 0, stream>>>(
      bufA, hb, wt + 3 * 16384, wt + 5 * 16384, sbl + HH, lng + HH, lnb + HH,
      wt + 6 * 16384, cb1, wt + 7 * 16384, cb2, out_h, out_logits);
}